// Round 9
// baseline (155.058 us; speedup 1.0000x reference)
//
#include <hip/hip_runtime.h>
#include <hip/hip_bf16.h>

// CARAFE++ downsample: B=8, C=128, H=W=160, stride 2 -> HD=WD=80
// Model from R7/R8 counters: wall = VMEM instruction issue (~2 inst/cyc/CU).
// Design rule: minimize VMEM instruction COUNT (float4 everywhere, LDS reuse).
#define B   8
#define C   128
#define H   160
#define W   160
#define HW  (H*W)       // 25600
#define CM  16
#define KC  25
#define HD  80
#define WD  80
#define HWD (HD*WD)     // 6400

// ---- stage 1: 1x1 conv 128->16. Thread = 4 pixels (float4); the 128 ci are
// split across the 4 waves (32 each, wave-uniform -> wc stays s_load); f4 LDS
// reduce. 800 blocks, VMEM ~3.3M insts total. ----
__global__ __launch_bounds__(256) void compress_k(const float* __restrict__ x,
                                                  const float* __restrict__ wc,
                                                  __hip_bfloat16* __restrict__ comp) {
    __shared__ float4 red[2][CM][64];               // 32 KB
    int lane = threadIdx.x & 63;
    int s    = __builtin_amdgcn_readfirstlane(threadIdx.x >> 6);  // wave id 0..3
    int gq   = blockIdx.x * 64 + lane;              // global pixel-quad
    int px0  = gq * 4;
    int b    = px0 / HW;
    int pos  = px0 % HW;
    const float* xb = x + (size_t)b * C * HW + pos;

    float4 acc[CM];
#pragma unroll
    for (int co = 0; co < CM; ++co) acc[co] = make_float4(0.f, 0.f, 0.f, 0.f);
#pragma unroll
    for (int g = 0; g < 2; ++g) {
        float4 v[16];
#pragma unroll
        for (int u = 0; u < 16; ++u) {              // 16 f4 loads in flight
            int ci = s * 32 + g * 16 + u;
            v[u] = *reinterpret_cast<const float4*>(xb + (size_t)ci * HW);
        }
#pragma unroll
        for (int u = 0; u < 16; ++u) {
            int ci = s * 32 + g * 16 + u;
#pragma unroll
            for (int co = 0; co < CM; ++co) {
                float wv = wc[co * C + ci];         // uniform -> s_load
                acc[co].x = fmaf(v[u].x, wv, acc[co].x);
                acc[co].y = fmaf(v[u].y, wv, acc[co].y);
                acc[co].z = fmaf(v[u].z, wv, acc[co].z);
                acc[co].w = fmaf(v[u].w, wv, acc[co].w);
            }
        }
    }
    // cross-wave reduce (s0+s2, s1+s3, then +): lane-major f4 -> conflict-free
    if (s >= 2) {
#pragma unroll
        for (int co = 0; co < CM; ++co) red[s - 2][co][lane] = acc[co];
    }
    __syncthreads();
    if (s < 2) {
#pragma unroll
        for (int co = 0; co < CM; ++co) {
            float4 r = red[s][co][lane];
            acc[co].x += r.x; acc[co].y += r.y; acc[co].z += r.z; acc[co].w += r.w;
        }
    }
    __syncthreads();
    if (s == 1) {
#pragma unroll
        for (int co = 0; co < CM; ++co) red[0][co][lane] = acc[co];
    }
    __syncthreads();
    if (s == 0) {
        __hip_bfloat16* cb = comp + (size_t)b * CM * HW + pos;
#pragma unroll
        for (int co = 0; co < CM; ++co) {
            float4 r = red[0][co][lane];
            float4 a = acc[co];
            union { __hip_bfloat16 h[4]; uint2 u; } pk;
            pk.h[0] = __float2bfloat16(a.x + r.x);
            pk.h[1] = __float2bfloat16(a.y + r.y);
            pk.h[2] = __float2bfloat16(a.z + r.z);
            pk.h[3] = __float2bfloat16(a.w + r.w);
            *reinterpret_cast<uint2*>(cb + co * HW) = pk.u;   // 8B store
        }
    }
}

// ---- stage 2: 3x3 s2 conv 16->25 + softmax; ci split across 4 waves.
// Output layout: ker_g[b][hq=20][tap=25][px=320] (tap-major per 4-row block)
// so reassemble stages it with coalesced f4 loads. ----
__global__ __launch_bounds__(256) void encoder_k(const __hip_bfloat16* __restrict__ comp,
                                                 const float* __restrict__ we,
                                                 float* __restrict__ ker_g) {
    __shared__ float part[4][KC][65];
    int lane = threadIdx.x & 63;
    int sub  = __builtin_amdgcn_readfirstlane(threadIdx.x >> 6);  // wave id, uniform
    int p  = blockIdx.x * 64 + lane;                // global pixel 0..51199
    int b  = p / HWD;
    int r2 = p % HWD;
    int hd = r2 / WD;
    int wd = r2 % WD;
    const __hip_bfloat16* cb = comp + (size_t)b * CM * HW;
    float acc[KC];
#pragma unroll
    for (int ko = 0; ko < KC; ++ko) acc[ko] = 0.f;
#pragma unroll
    for (int cii = 0; cii < 4; ++cii) {
        int ci = sub * 4 + cii;                     // uniform -> we stays s_load
#pragma unroll
        for (int kh = 0; kh < 3; ++kh) {
            int r    = 2 * hd + kh - 1;
            bool rok = (unsigned)r < H;
            int rc   = min(max(r, 0), H - 1);
#pragma unroll
            for (int kw = 0; kw < 3; ++kw) {
                int c0  = 2 * wd + kw - 1;
                bool ok = rok && ((unsigned)c0 < W);
                int cc  = min(max(c0, 0), W - 1);
                float cv = __bfloat162float(cb[(size_t)ci * HW + rc * W + cc]);
                cv = ok ? cv : 0.f;
#pragma unroll
                for (int ko = 0; ko < KC; ++ko)
                    acc[ko] = fmaf(cv, we[((ko * CM + ci) * 3 + kh) * 3 + kw], acc[ko]);
            }
        }
    }
#pragma unroll
    for (int ko = 0; ko < KC; ++ko) part[sub][ko][lane] = acc[ko];
    __syncthreads();
    if (threadIdx.x < 64) {
        float a[KC];
#pragma unroll
        for (int ko = 0; ko < KC; ++ko)
            a[ko] = (part[0][ko][lane] + part[1][ko][lane]) +
                    (part[2][ko][lane] + part[3][ko][lane]);
        float m = a[0];
#pragma unroll
        for (int ko = 1; ko < KC; ++ko) m = fmaxf(m, a[ko]);
        float s = 0.f;
#pragma unroll
        for (int ko = 0; ko < KC; ++ko) { a[ko] = __expf(a[ko] - m); s += a[ko]; }
        float inv = 1.f / s;
#pragma unroll
        for (int ko = 0; ko < KC; ++ko) part[0][ko][lane] = a[ko] * inv;
    }
    __syncthreads();
    // tap-major store: block's 64 pixels lie inside ONE hq-block (320 | 6400)
    int P0  = blockIdx.x * 64;
    int bb  = P0 / HWD;
    int rem = P0 % HWD;
    int hq  = rem / 320;
    int pl0 = rem % 320;
    float* kout = ker_g + (((size_t)bb * 20 + hq) * KC) * 320 + pl0;
    for (int t = threadIdx.x; t < 64 * KC; t += 256) {
        int ko = t / 64, pix = t % 64;
        kout[ko * 320 + pix] = part[0][ko][pix];    // coalesced per 64
    }
}

// ---- stage 3: 5x5 s2 reassembly, LDS-tiled. Block = (b, hq: 4 hd rows,
// cg: 4 channels) x all 80 wd. x window zero-padded in LDS (no masks);
// ker slice tap-major in LDS (f4 covers 4 pixels per read). ----
__global__ __launch_bounds__(320, 2) void reassemble_k(const float* __restrict__ x,
                                                       const float* __restrict__ ker_g,
                                                       float* __restrict__ out) {
    __shared__ float xl[4][11][168];                // 29.57 KB, zero-padded cols/rows
    __shared__ float kl[KC][320];                   // 32.0 KB, tap-major
    int bid = blockIdx.x;
    int cg  = bid & 31;                             // channel group (4 ch)
    int t2  = bid >> 5;
    int hq  = t2 % 20;                              // 4-row block
    int b   = t2 / 20;

    // stage x: 4 ch x 11 rows x 42 f4 (lcol = col+4; f==0/41 and OOB rows = 0)
    for (int t = threadIdx.x; t < 1848; t += 320) {
        int ch  = t / 462;                          // 462 = 11*42
        int r   = t % 462;
        int row = r / 42, f = r % 42;
        int gr  = hq * 8 - 2 + row;
        float4 v = make_float4(0.f, 0.f, 0.f, 0.f);
        if (f >= 1 && f <= 40 && (unsigned)gr < H)
            v = *reinterpret_cast<const float4*>(
                x + (size_t)(b * C + cg * 4 + ch) * HW + gr * W + (f - 1) * 4);
        *reinterpret_cast<float4*>(&xl[ch][row][f * 4]) = v;
    }
    // stage ker: layouts identical ([25][320] f32 = 2000 f4), pure f4 copy
    const float4* kg4 = reinterpret_cast<const float4*>(
        ker_g + ((size_t)(b * 20 + hq) * KC) * 320);
    float4* kl4 = reinterpret_cast<float4*>(&kl[0][0]);
    for (int t = threadIdx.x; t < 2000; t += 320)
        kl4[t] = kg4[t];
    __syncthreads();

    // compute: thread = (hd, q, c): 4 outputs (wd = 4q..4q+3), 1 channel
    int c  = threadIdx.x & 3;
    int t3 = threadIdx.x >> 2;                      // 0..79
    int q  = t3 % 20;
    int hd = t3 / 20;
    int px0 = hd * 80 + 4 * q;
    float acc0 = 0.f, acc1 = 0.f, acc2 = 0.f, acc3 = 0.f;
#pragma unroll
    for (int i = 0; i < 5; ++i) {
        int lr = 2 * hd + i;
        const float* wrow = &xl[c][lr][8 * q];      // window lc 8q+2..8q+12
        float4 a  = *reinterpret_cast<const float4*>(wrow);
        float4 bq = *reinterpret_cast<const float4*>(wrow + 4);
        float4 cq = *reinterpret_cast<const float4*>(wrow + 8);
        float  dq = wrow[12];
        float w[13] = {a.x, a.y, a.z, a.w, bq.x, bq.y, bq.z, bq.w,
                       cq.x, cq.y, cq.z, cq.w, dq};
#pragma unroll
        for (int j = 0; j < 5; ++j) {
            float4 kt = *reinterpret_cast<const float4*>(&kl[i * 5 + j][px0]);
            acc0 = fmaf(w[2 + j], kt.x, acc0);      // out p: x col lc = 8q+2p+j+2
            acc1 = fmaf(w[4 + j], kt.y, acc1);
            acc2 = fmaf(w[6 + j], kt.z, acc2);
            acc3 = fmaf(w[8 + j], kt.w, acc3);
        }
    }
    *reinterpret_cast<float4*>(
        out + ((size_t)(b * C + cg * 4 + c) * HD + hq * 4 + hd) * WD + 4 * q) =
        make_float4(acc0, acc1, acc2, acc3);
}

extern "C" void kernel_launch(void* const* d_in, const int* in_sizes, int n_in,
                              void* d_out, int out_size, void* d_ws, size_t ws_size,
                              hipStream_t stream) {
    const float* x  = (const float*)d_in[0];
    const float* wc = (const float*)d_in[1];
    const float* we = (const float*)d_in[2];
    float* out = (float*)d_out;
    __hip_bfloat16* comp = (__hip_bfloat16*)d_ws;         // B*CM*HW bf16 = 6.55 MB
    float* ker_g = (float*)((char*)d_ws + (size_t)B * CM * HW * sizeof(__hip_bfloat16));
                                                          // B*20*25*320 f32 = 5.12 MB

    compress_k  <<<(B * HW / 4) / 64, 256, 0, stream>>>(x, wc, comp);    // 800 blocks
    encoder_k   <<<(B * HWD) / 64,    256, 0, stream>>>(comp, we, ker_g);// 800 blocks
    reassemble_k<<<B * 20 * 32,       320, 0, stream>>>(x, ker_g, out);  // 5120 blocks
}

// Round 10
// 99.749 us; speedup vs baseline: 1.5545x; 1.5545x over previous
//
#include <hip/hip_runtime.h>
#include <hip/hip_bf16.h>

// CARAFE++ downsample: B=8, C=128, H=W=160, stride 2 -> HD=WD=80
// Model (R7-R9 counters): pair-based reassembles were TA-bound (64B lane
// stride = 64 lines/wave-inst); R9 fixed that via LDS staging but hit bank
// conflicts (11.4M) + 2 blocks/CU. This round: padded xl banks + bf16 kl
// (46.3KB -> 3 blocks/CU).
#define B   8
#define C   128
#define H   160
#define W   160
#define HW  (H*W)       // 25600
#define CM  16
#define KC  25
#define HD  80
#define WD  80
#define HWD (HD*WD)     // 6400
#define XPAD 172        // xl row stride (mod 32 = 12; c-stride 1892 mod 32 = 4)

// ---- stage 1: 1x1 conv 128->16. Thread = 4 pixels (float4); ci split
// across 4 waves; f4 LDS reduce. ----
__global__ __launch_bounds__(256) void compress_k(const float* __restrict__ x,
                                                  const float* __restrict__ wc,
                                                  __hip_bfloat16* __restrict__ comp) {
    __shared__ float4 red[2][CM][64];               // 32 KB
    int lane = threadIdx.x & 63;
    int s    = __builtin_amdgcn_readfirstlane(threadIdx.x >> 6);  // wave id 0..3
    int gq   = blockIdx.x * 64 + lane;              // global pixel-quad
    int px0  = gq * 4;
    int b    = px0 / HW;
    int pos  = px0 % HW;
    const float* xb = x + (size_t)b * C * HW + pos;

    float4 acc[CM];
#pragma unroll
    for (int co = 0; co < CM; ++co) acc[co] = make_float4(0.f, 0.f, 0.f, 0.f);
#pragma unroll
    for (int g = 0; g < 2; ++g) {
        float4 v[16];
#pragma unroll
        for (int u = 0; u < 16; ++u) {              // 16 f4 loads in flight
            int ci = s * 32 + g * 16 + u;
            v[u] = *reinterpret_cast<const float4*>(xb + (size_t)ci * HW);
        }
#pragma unroll
        for (int u = 0; u < 16; ++u) {
            int ci = s * 32 + g * 16 + u;
#pragma unroll
            for (int co = 0; co < CM; ++co) {
                float wv = wc[co * C + ci];         // uniform -> s_load
                acc[co].x = fmaf(v[u].x, wv, acc[co].x);
                acc[co].y = fmaf(v[u].y, wv, acc[co].y);
                acc[co].z = fmaf(v[u].z, wv, acc[co].z);
                acc[co].w = fmaf(v[u].w, wv, acc[co].w);
            }
        }
    }
    if (s >= 2) {
#pragma unroll
        for (int co = 0; co < CM; ++co) red[s - 2][co][lane] = acc[co];
    }
    __syncthreads();
    if (s < 2) {
#pragma unroll
        for (int co = 0; co < CM; ++co) {
            float4 r = red[s][co][lane];
            acc[co].x += r.x; acc[co].y += r.y; acc[co].z += r.z; acc[co].w += r.w;
        }
    }
    __syncthreads();
    if (s == 1) {
#pragma unroll
        for (int co = 0; co < CM; ++co) red[0][co][lane] = acc[co];
    }
    __syncthreads();
    if (s == 0) {
        __hip_bfloat16* cb = comp + (size_t)b * CM * HW + pos;
#pragma unroll
        for (int co = 0; co < CM; ++co) {
            float4 r = red[0][co][lane];
            float4 a = acc[co];
            union { __hip_bfloat16 h[4]; uint2 u; } pk;
            pk.h[0] = __float2bfloat16(a.x + r.x);
            pk.h[1] = __float2bfloat16(a.y + r.y);
            pk.h[2] = __float2bfloat16(a.z + r.z);
            pk.h[3] = __float2bfloat16(a.w + r.w);
            *reinterpret_cast<uint2*>(cb + co * HW) = pk.u;   // 8B store
        }
    }
}

// ---- stage 2: 3x3 s2 conv 16->25 + softmax; ci split across 4 waves.
// Output: ker_g[b][hq=20][tap=25][px=320] in BF16 (tap-major per 4-row blk). ----
__global__ __launch_bounds__(256) void encoder_k(const __hip_bfloat16* __restrict__ comp,
                                                 const float* __restrict__ we,
                                                 __hip_bfloat16* __restrict__ ker_g) {
    __shared__ float part[4][KC][65];
    int lane = threadIdx.x & 63;
    int sub  = __builtin_amdgcn_readfirstlane(threadIdx.x >> 6);  // wave id, uniform
    int p  = blockIdx.x * 64 + lane;                // global pixel 0..51199
    int b  = p / HWD;
    int r2 = p % HWD;
    int hd = r2 / WD;
    int wd = r2 % WD;
    const __hip_bfloat16* cb = comp + (size_t)b * CM * HW;
    float acc[KC];
#pragma unroll
    for (int ko = 0; ko < KC; ++ko) acc[ko] = 0.f;
#pragma unroll
    for (int cii = 0; cii < 4; ++cii) {
        int ci = sub * 4 + cii;                     // uniform -> we stays s_load
#pragma unroll
        for (int kh = 0; kh < 3; ++kh) {
            int r    = 2 * hd + kh - 1;
            bool rok = (unsigned)r < H;
            int rc   = min(max(r, 0), H - 1);
#pragma unroll
            for (int kw = 0; kw < 3; ++kw) {
                int c0  = 2 * wd + kw - 1;
                bool ok = rok && ((unsigned)c0 < W);
                int cc  = min(max(c0, 0), W - 1);
                float cv = __bfloat162float(cb[(size_t)ci * HW + rc * W + cc]);
                cv = ok ? cv : 0.f;
#pragma unroll
                for (int ko = 0; ko < KC; ++ko)
                    acc[ko] = fmaf(cv, we[((ko * CM + ci) * 3 + kh) * 3 + kw], acc[ko]);
            }
        }
    }
#pragma unroll
    for (int ko = 0; ko < KC; ++ko) part[sub][ko][lane] = acc[ko];
    __syncthreads();
    if (threadIdx.x < 64) {
        float a[KC];
#pragma unroll
        for (int ko = 0; ko < KC; ++ko)
            a[ko] = (part[0][ko][lane] + part[1][ko][lane]) +
                    (part[2][ko][lane] + part[3][ko][lane]);
        float m = a[0];
#pragma unroll
        for (int ko = 1; ko < KC; ++ko) m = fmaxf(m, a[ko]);
        float s = 0.f;
#pragma unroll
        for (int ko = 0; ko < KC; ++ko) { a[ko] = __expf(a[ko] - m); s += a[ko]; }
        float inv = 1.f / s;
#pragma unroll
        for (int ko = 0; ko < KC; ++ko) part[0][ko][lane] = a[ko] * inv;
    }
    __syncthreads();
    // tap-major bf16 store: block's 64 pixels lie inside ONE hq-block
    int P0  = blockIdx.x * 64;
    int bb  = P0 / HWD;
    int rem = P0 % HWD;
    int hq  = rem / 320;
    int pl0 = rem % 320;
    __hip_bfloat16* kout = ker_g + (((size_t)bb * 20 + hq) * KC) * 320 + pl0;
    for (int t = threadIdx.x; t < 64 * KC; t += 256) {
        int ko = t / 64, pix = t % 64;
        kout[ko * 320 + pix] = __float2bfloat16(part[0][ko][pix]);
    }
}

// ---- stage 3: 5x5 s2 reassembly, LDS-tiled, bank-fixed. Block = (b, hq,
// cg: 4 ch) x 80 wd. xl padded (XPAD=172) -> <=2-way banks; kl bf16 16KB.
// LDS 46.3KB -> 3 blocks/CU. All global loads lane-contiguous f4. ----
__global__ __launch_bounds__(320) void reassemble_k(const float* __restrict__ x,
                                                    const __hip_bfloat16* __restrict__ ker_g,
                                                    float* __restrict__ out) {
    __shared__ float xl[4][11][XPAD];               // 30.3 KB, zero-padded
    __shared__ __hip_bfloat16 kl[KC * 320];         // 16.0 KB, tap-major
    int bid = blockIdx.x;
    int cg  = bid & 31;                             // channel group (4 ch)
    int t2  = bid >> 5;
    int hq  = t2 % 20;                              // 4-row output block
    int b   = t2 / 20;

    // stage x: 4 ch x 11 rows x 42 f4 (lds col = global col + 4; OOB = 0)
    for (int t = threadIdx.x; t < 1848; t += 320) {
        int ch  = t / 462;                          // 462 = 11*42
        int r   = t % 462;
        int row = r / 42, f = r % 42;
        int gr  = hq * 8 - 2 + row;
        float4 v = make_float4(0.f, 0.f, 0.f, 0.f);
        if (f >= 1 && f <= 40 && (unsigned)gr < H)
            v = *reinterpret_cast<const float4*>(
                x + (size_t)(b * C + cg * 4 + ch) * HW + gr * W + (f - 1) * 4);
        *reinterpret_cast<float4*>(&xl[ch][row][f * 4]) = v;
    }
    // stage ker: 25x320 bf16 = 1000 uint4, lane-contiguous
    {
        const uint4* kg4 = reinterpret_cast<const uint4*>(
            ker_g + ((size_t)(b * 20 + hq) * KC) * 320);
        uint4* kl4 = reinterpret_cast<uint4*>(kl);
        for (int t = threadIdx.x; t < 1000; t += 320)
            kl4[t] = kg4[t];
    }
    __syncthreads();

    // compute: thread = (hd, q, c): 4 outputs (wd = 4q..4q+3), 1 channel
    int c  = threadIdx.x & 3;
    int t3 = threadIdx.x >> 2;                      // 0..79
    int q  = t3 % 20;
    int hd = t3 / 20;
    int px0 = hd * 80 + 4 * q;                      // local pixel of output 0
    float acc0 = 0.f, acc1 = 0.f, acc2 = 0.f, acc3 = 0.f;
#pragma unroll
    for (int i = 0; i < 5; ++i) {
        int lr = 2 * hd + i;
        const float* wrow = &xl[c][lr][8 * q];      // window cols 8q-4.. (lds)
        float4 a  = *reinterpret_cast<const float4*>(wrow);
        float4 bq = *reinterpret_cast<const float4*>(wrow + 4);
        float4 cq = *reinterpret_cast<const float4*>(wrow + 8);
        float  dq = wrow[12];
        float w[13] = {a.x, a.y, a.z, a.w, bq.x, bq.y, bq.z, bq.w,
                       cq.x, cq.y, cq.z, cq.w, dq};
#pragma unroll
        for (int j = 0; j < 5; ++j) {
            // 4 bf16 kernel values for the 4 outputs (8B LDS read)
            uint2 ku = *reinterpret_cast<const uint2*>(&kl[(i * 5 + j) * 320 + px0]);
            float k0 = __uint_as_float((ku.x & 0xFFFFu) << 16);
            float k1 = __uint_as_float(ku.x & 0xFFFF0000u);
            float k2 = __uint_as_float((ku.y & 0xFFFFu) << 16);
            float k3 = __uint_as_float(ku.y & 0xFFFF0000u);
            acc0 = fmaf(w[2 + j], k0, acc0);        // out p reads lds col 8q+2p+j+2
            acc1 = fmaf(w[4 + j], k1, acc1);
            acc2 = fmaf(w[6 + j], k2, acc2);
            acc3 = fmaf(w[8 + j], k3, acc3);
        }
    }
    *reinterpret_cast<float4*>(
        out + ((size_t)(b * C + cg * 4 + c) * HD + hq * 4 + hd) * WD + 4 * q) =
        make_float4(acc0, acc1, acc2, acc3);
}

extern "C" void kernel_launch(void* const* d_in, const int* in_sizes, int n_in,
                              void* d_out, int out_size, void* d_ws, size_t ws_size,
                              hipStream_t stream) {
    const float* x  = (const float*)d_in[0];
    const float* wc = (const float*)d_in[1];
    const float* we = (const float*)d_in[2];
    float* out = (float*)d_out;
    __hip_bfloat16* comp  = (__hip_bfloat16*)d_ws;        // B*CM*HW bf16 = 6.55 MB
    __hip_bfloat16* ker_g = comp + (size_t)B * CM * HW;   // B*20*25*320 bf16 = 2.56 MB

    compress_k  <<<(B * HW / 4) / 64, 256, 0, stream>>>(x, wc, comp);    // 800 blocks
    encoder_k   <<<(B * HWD) / 64,    256, 0, stream>>>(comp, we, ker_g);// 800 blocks
    reassemble_k<<<B * 20 * 32,       320, 0, stream>>>(x, ker_g, out);  // 5120 blocks
}

// Round 11
// 82.621 us; speedup vs baseline: 1.8767x; 1.2073x over previous
//
#include <hip/hip_runtime.h>
#include <hip/hip_bf16.h>

// CARAFE++ downsample: B=8, C=128, H=W=160, stride 2 -> HD=WD=80
// R10 counters: reassemble split ~evenly across VALU (bf16 unpack), LDS pipe
// (45 reads/thread + conflicts) and latency. This round: f16 staging +
// v_dot2_f32_f16 -> 25 LDS reads + 60 dot2 per thread, 34.7KB LDS (4 blk/CU).
#define B   8
#define C   128
#define H   160
#define W   160
#define HW  (H*W)       // 25600
#define CM  16
#define KC  25
#define HD  80
#define WD  80
#define HWD (HD*WD)     // 6400

typedef __fp16 half2_t __attribute__((ext_vector_type(2)));
union H2U { uint u; half2_t h; };

static __device__ __forceinline__ float dot2f(uint a, uint b, float c) {
    H2U ua, ub; ua.u = a; ub.u = b;
#if __has_builtin(__builtin_amdgcn_fdot2)
    return __builtin_amdgcn_fdot2(ua.h, ub.h, c, false);
#else
    return fmaf((float)ua.h.x, (float)ub.h.x, fmaf((float)ua.h.y, (float)ub.h.y, c));
#endif
}
static __device__ __forceinline__ uint pk16(float a, float b) {
    H2U r; r.h = __builtin_amdgcn_cvt_pkrtz(a, b); return r.u;
}

// ---- stage 1: 1x1 conv 128->16. Thread = 4 pixels (float4); ci split
// across 4 waves; f4 LDS reduce. (unchanged from R10) ----
__global__ __launch_bounds__(256) void compress_k(const float* __restrict__ x,
                                                  const float* __restrict__ wc,
                                                  __hip_bfloat16* __restrict__ comp) {
    __shared__ float4 red[2][CM][64];               // 32 KB
    int lane = threadIdx.x & 63;
    int s    = __builtin_amdgcn_readfirstlane(threadIdx.x >> 6);  // wave id 0..3
    int gq   = blockIdx.x * 64 + lane;              // global pixel-quad
    int px0  = gq * 4;
    int b    = px0 / HW;
    int pos  = px0 % HW;
    const float* xb = x + (size_t)b * C * HW + pos;

    float4 acc[CM];
#pragma unroll
    for (int co = 0; co < CM; ++co) acc[co] = make_float4(0.f, 0.f, 0.f, 0.f);
#pragma unroll
    for (int g = 0; g < 2; ++g) {
        float4 v[16];
#pragma unroll
        for (int u = 0; u < 16; ++u) {              // 16 f4 loads in flight
            int ci = s * 32 + g * 16 + u;
            v[u] = *reinterpret_cast<const float4*>(xb + (size_t)ci * HW);
        }
#pragma unroll
        for (int u = 0; u < 16; ++u) {
            int ci = s * 32 + g * 16 + u;
#pragma unroll
            for (int co = 0; co < CM; ++co) {
                float wv = wc[co * C + ci];         // uniform -> s_load
                acc[co].x = fmaf(v[u].x, wv, acc[co].x);
                acc[co].y = fmaf(v[u].y, wv, acc[co].y);
                acc[co].z = fmaf(v[u].z, wv, acc[co].z);
                acc[co].w = fmaf(v[u].w, wv, acc[co].w);
            }
        }
    }
    if (s >= 2) {
#pragma unroll
        for (int co = 0; co < CM; ++co) red[s - 2][co][lane] = acc[co];
    }
    __syncthreads();
    if (s < 2) {
#pragma unroll
        for (int co = 0; co < CM; ++co) {
            float4 r = red[s][co][lane];
            acc[co].x += r.x; acc[co].y += r.y; acc[co].z += r.z; acc[co].w += r.w;
        }
    }
    __syncthreads();
    if (s == 1) {
#pragma unroll
        for (int co = 0; co < CM; ++co) red[0][co][lane] = acc[co];
    }
    __syncthreads();
    if (s == 0) {
        __hip_bfloat16* cb = comp + (size_t)b * CM * HW + pos;
#pragma unroll
        for (int co = 0; co < CM; ++co) {
            float4 r = red[0][co][lane];
            float4 a = acc[co];
            union { __hip_bfloat16 h[4]; uint2 u; } pk;
            pk.h[0] = __float2bfloat16(a.x + r.x);
            pk.h[1] = __float2bfloat16(a.y + r.y);
            pk.h[2] = __float2bfloat16(a.z + r.z);
            pk.h[3] = __float2bfloat16(a.w + r.w);
            *reinterpret_cast<uint2*>(cb + co * HW) = pk.u;   // 8B store
        }
    }
}

// ---- stage 2: 3x3 s2 conv 16->25 + softmax; ci split across 4 waves.
// Output ker_g layout: [b][hq=20][slot=15][px=320] u32, slot = i*3+jp,
// u32 = f16 pair (tap i*5+jp*2, i*5+jp*2+1), jp=2 pairs (tap4, 0). ----
__global__ __launch_bounds__(256) void encoder_k(const __hip_bfloat16* __restrict__ comp,
                                                 const float* __restrict__ we,
                                                 uint* __restrict__ ker_g) {
    __shared__ float part[4][KC][65];
    int lane = threadIdx.x & 63;
    int sub  = __builtin_amdgcn_readfirstlane(threadIdx.x >> 6);  // wave id, uniform
    int p  = blockIdx.x * 64 + lane;                // global pixel 0..51199
    int b  = p / HWD;
    int r2 = p % HWD;
    int hd = r2 / WD;
    int wd = r2 % WD;
    const __hip_bfloat16* cb = comp + (size_t)b * CM * HW;
    float acc[KC];
#pragma unroll
    for (int ko = 0; ko < KC; ++ko) acc[ko] = 0.f;
#pragma unroll
    for (int cii = 0; cii < 4; ++cii) {
        int ci = sub * 4 + cii;                     // uniform -> we stays s_load
#pragma unroll
        for (int kh = 0; kh < 3; ++kh) {
            int r    = 2 * hd + kh - 1;
            bool rok = (unsigned)r < H;
            int rc   = min(max(r, 0), H - 1);
#pragma unroll
            for (int kw = 0; kw < 3; ++kw) {
                int c0  = 2 * wd + kw - 1;
                bool ok = rok && ((unsigned)c0 < W);
                int cc  = min(max(c0, 0), W - 1);
                float cv = __bfloat162float(cb[(size_t)ci * HW + rc * W + cc]);
                cv = ok ? cv : 0.f;
#pragma unroll
                for (int ko = 0; ko < KC; ++ko)
                    acc[ko] = fmaf(cv, we[((ko * CM + ci) * 3 + kh) * 3 + kw], acc[ko]);
            }
        }
    }
#pragma unroll
    for (int ko = 0; ko < KC; ++ko) part[sub][ko][lane] = acc[ko];
    __syncthreads();
    if (threadIdx.x < 64) {
        float a[KC];
#pragma unroll
        for (int ko = 0; ko < KC; ++ko)
            a[ko] = (part[0][ko][lane] + part[1][ko][lane]) +
                    (part[2][ko][lane] + part[3][ko][lane]);
        float m = a[0];
#pragma unroll
        for (int ko = 1; ko < KC; ++ko) m = fmaxf(m, a[ko]);
        float s = 0.f;
#pragma unroll
        for (int ko = 0; ko < KC; ++ko) { a[ko] = __expf(a[ko] - m); s += a[ko]; }
        float inv = 1.f / s;
#pragma unroll
        for (int ko = 0; ko < KC; ++ko) part[0][ko][lane] = a[ko] * inv;
    }
    __syncthreads();
    // paired-f16 store: block's 64 pixels lie inside ONE hq-block (320|6400)
    int P0  = blockIdx.x * 64;
    int bb  = P0 / HWD;
    int rem = P0 % HWD;
    int hq  = rem / 320;
    int pl0 = rem % 320;
    uint* kout = ker_g + ((size_t)(bb * 20 + hq) * 15) * 320 + pl0;
    for (int t = threadIdx.x; t < 64 * 15; t += 256) {
        int slot = t / 64, pix = t % 64;
        int i = slot / 3, jp = slot % 3;
        int t0 = i * 5 + jp * 2;
        float k0 = part[0][t0][pix];
        float k1 = (jp < 2) ? part[0][t0 + 1][pix] : 0.f;
        kout[slot * 320 + pix] = pk16(k0, k1);      // coalesced 4B
    }
}

// ---- stage 3: 5x5 s2 reassembly, f16 LDS + dot2. Block = (b, hq, cg:4ch)
// x 80 wd. xl f16 [4][11][176] (15.1KB), kl u32 [15][320] (19.2KB) ->
// 34.7KB -> 4 blocks/CU. Per thread: 25 LDS reads + 60 v_dot2. ----
__global__ __launch_bounds__(320) void reassemble_k(const float* __restrict__ x,
                                                    const uint* __restrict__ ker_g,
                                                    float* __restrict__ out) {
    __shared__ uint xls[4][11][88];                 // 88 u32 = 176 f16/row
    __shared__ uint kls[15][320];                   // tap-pair major
    int bid = blockIdx.x;
    int cg  = bid & 31;                             // channel group (4 ch)
    int t2  = bid >> 5;
    int hq  = t2 % 20;                              // 4-row output block
    int b   = t2 / 20;

    // stage x: 4 ch x 11 rows x 42 f4 -> f16 (lds col = gcol+4; OOB = 0)
    for (int t = threadIdx.x; t < 1848; t += 320) {
        int ch  = t / 462;                          // 462 = 11*42
        int r   = t % 462;
        int row = r / 42, f = r % 42;
        int gr  = hq * 8 - 2 + row;
        float4 v = make_float4(0.f, 0.f, 0.f, 0.f);
        if (f >= 1 && f <= 40 && (unsigned)gr < H)
            v = *reinterpret_cast<const float4*>(
                x + (size_t)(b * C + cg * 4 + ch) * HW + gr * W + (f - 1) * 4);
        uint2 hv = make_uint2(pk16(v.x, v.y), pk16(v.z, v.w));
        *reinterpret_cast<uint2*>(&xls[ch][row][f * 2]) = hv;   // 8B aligned
    }
    // stage ker: 15*320 u32 = 1200 uint4, lane-contiguous
    {
        const uint4* kg4 = reinterpret_cast<const uint4*>(
            ker_g + ((size_t)(b * 20 + hq) * 15) * 320);
        uint4* kl4 = reinterpret_cast<uint4*>(&kls[0][0]);
        for (int t = threadIdx.x; t < 1200; t += 320)
            kl4[t] = kg4[t];
    }
    __syncthreads();

    // compute: thread = (hd, q, c): 4 outputs (wd = 4q..4q+3), 1 channel
    int c  = threadIdx.x & 3;
    int t3 = threadIdx.x >> 2;                      // 0..79
    int q  = t3 % 20;
    int hd = t3 / 20;
    int px0 = hd * 80 + 4 * q;                      // local pixel of output 0
    float a0 = 0.f, a1 = 0.f, a2 = 0.f, a3 = 0.f;
#pragma unroll
    for (int i = 0; i < 5; ++i) {
        int lr = 2 * hd + i;
        // x window: f16 elements 8q..8q+15 (dwords xd[0..7]); output p uses
        // element pairs (8q+2p+2+j,+1): j01 -> xd[p+1], j23 -> xd[p+2], j4 -> xd[p+3]
        const uint* xrow = &xls[c][lr][4 * q];
        uint4 xa = *reinterpret_cast<const uint4*>(xrow);       // 16B aligned
        uint4 xb = *reinterpret_cast<const uint4*>(xrow + 4);
        uint xd[8] = {xa.x, xa.y, xa.z, xa.w, xb.x, xb.y, xb.z, xb.w};
        uint4 k0 = *reinterpret_cast<const uint4*>(&kls[i * 3 + 0][px0]);
        uint4 k1 = *reinterpret_cast<const uint4*>(&kls[i * 3 + 1][px0]);
        uint4 k2 = *reinterpret_cast<const uint4*>(&kls[i * 3 + 2][px0]);
        a0 = dot2f(xd[1], k0.x, a0); a0 = dot2f(xd[2], k1.x, a0); a0 = dot2f(xd[3], k2.x, a0);
        a1 = dot2f(xd[2], k0.y, a1); a1 = dot2f(xd[3], k1.y, a1); a1 = dot2f(xd[4], k2.y, a1);
        a2 = dot2f(xd[3], k0.z, a2); a2 = dot2f(xd[4], k1.z, a2); a2 = dot2f(xd[5], k2.z, a2);
        a3 = dot2f(xd[4], k0.w, a3); a3 = dot2f(xd[5], k1.w, a3); a3 = dot2f(xd[6], k2.w, a3);
    }
    *reinterpret_cast<float4*>(
        out + ((size_t)(b * C + cg * 4 + c) * HD + hq * 4 + hd) * WD + 4 * q) =
        make_float4(a0, a1, a2, a3);
}

extern "C" void kernel_launch(void* const* d_in, const int* in_sizes, int n_in,
                              void* d_out, int out_size, void* d_ws, size_t ws_size,
                              hipStream_t stream) {
    const float* x  = (const float*)d_in[0];
    const float* wc = (const float*)d_in[1];
    const float* we = (const float*)d_in[2];
    float* out = (float*)d_out;
    __hip_bfloat16* comp = (__hip_bfloat16*)d_ws;         // B*CM*HW bf16 = 6.55 MB
    uint* ker_g = (uint*)((char*)d_ws + (size_t)B * CM * HW * sizeof(__hip_bfloat16));
                                                          // B*20*15*320 u32 = 6.14 MB

    compress_k  <<<(B * HW / 4) / 64, 256, 0, stream>>>(x, wc, comp);    // 800 blocks
    encoder_k   <<<(B * HWD) / 64,    256, 0, stream>>>(comp, we, ker_g);// 800 blocks
    reassemble_k<<<B * 20 * 32,       320, 0, stream>>>(x, ker_g, out);  // 5120 blocks
}